// Round 9
// baseline (475.726 us; speedup 1.0000x reference)
//
#include <hip/hip_runtime.h>
#include <math.h>

#define N_ROWS 8192
#define IN_SZ 256
#define HID 128
#define INV_TEMP 5.0f
#define EPSV 1e-8f

typedef _Float16 half8 __attribute__((ext_vector_type(8)));
typedef float f32x4 __attribute__((ext_vector_type(4)));

__device__ __forceinline__ ushort f2h(float v) {
    union { _Float16 h; ushort u; } c;
    c.h = (_Float16)v;
    return c.u;
}

// async global->LDS, 16 B per lane; LDS dest = uniform base + lane*16
__device__ __forceinline__ void gl2lds16(const void* g, void* l) {
    __builtin_amdgcn_global_load_lds(
        (const __attribute__((address_space(1))) unsigned*)g,
        (__attribute__((address_space(3))) unsigned*)l, 16, 0, 0);
}

// ---------------------------------------------------------------------------
// Kernel 1 (prep): phase A = projection + L2 norm + fp16 emit (all blocks);
// phase B = grid-stride bit-pack of pos (256 MB -> 8 MB, BW-bound, overlaps
// proj stragglers; MLP-rich loop so 12 waves/CU still saturates HBM).
// Blocks 0-3 zero the sums accumulators.
// ---------------------------------------------------------------------------
__global__ __launch_bounds__(256) void prep_kernel(
    const float* __restrict__ z_mp, const float* __restrict__ z_sc,
    const float* __restrict__ W1, const float* __restrict__ b1,
    const float* __restrict__ W2, const float* __restrict__ b2,
    ushort* __restrict__ h_mp, ushort* __restrict__ h_sc,
    const int* __restrict__ pos, unsigned* __restrict__ posbits,
    float* __restrict__ sums)
{
    __shared__ float smem[10368];
    float* sZ  = smem;           // phase1: [k][m] 64 x 34 (pad)
    float* sW  = smem + 2176;    // phase1: [k][c] 64 x 128
    float* sH  = smem;           // phase2: [c][m] 128 x 33 (pad)
    float* sW2 = smem + 4224;    // phase2: [k2][c] 32 x 128
    float* snorm = smem + 8320;  // [32]

    const int t = threadIdx.x;
    const int sel = blockIdx.y;
    const int R0 = blockIdx.x * 32;
    const int tx = t & 15, ty = t >> 4;
    const int linb = blockIdx.y * gridDim.x + blockIdx.x;   // 0..511
    const float* z = (sel == 0) ? z_mp : z_sc;
    ushort* outH   = (sel == 0) ? h_mp : h_sc;

    if (linb < 4) {
        float4 z4 = make_float4(0.f, 0.f, 0.f, 0.f);
        float* base = sums + (size_t)linb * 8192 + t * 32;
#pragma unroll
        for (int i = 0; i < 8; ++i) *(float4*)(base + i * 4) = z4;
    }

    if (t < 32) snorm[t] = 0.f;

    float acc[2][8];
#pragma unroll
    for (int i = 0; i < 2; ++i)
#pragma unroll
        for (int j = 0; j < 8; ++j) acc[i][j] = 0.f;

    // GEMM1: H = ELU(Z @ W1 + b1)
    for (int ch = 0; ch < 4; ++ch) {
#pragma unroll
        for (int it = 0; it < 2; ++it) {
            int idx = it * 256 + t;
            int k4 = idx >> 5;
            int m  = idx & 31;
            float4 v = *(const float4*)(z + (size_t)(R0 + m) * IN_SZ + ch * 64 + k4 * 4);
            sZ[(k4 * 4 + 0) * 34 + m] = v.x;
            sZ[(k4 * 4 + 1) * 34 + m] = v.y;
            sZ[(k4 * 4 + 2) * 34 + m] = v.z;
            sZ[(k4 * 4 + 3) * 34 + m] = v.w;
        }
#pragma unroll
        for (int it = 0; it < 8; ++it) {
            int idx = it * 256 + t;
            int kk = idx >> 5;
            int c4 = idx & 31;
            *(float4*)(sW + kk * 128 + c4 * 4) =
                *(const float4*)(W1 + (size_t)(ch * 64 + kk) * HID + c4 * 4);
        }
        __syncthreads();
#pragma unroll 4
        for (int k = 0; k < 64; ++k) {
            float2 a = *(const float2*)(sZ + k * 34 + ty * 2);
            float4 b0 = *(float4*)(sW + k * 128 + tx * 4);
            float4 b1v = *(float4*)(sW + k * 128 + 64 + tx * 4);
            float av[2] = {a.x, a.y};
            float bv[8] = {b0.x, b0.y, b0.z, b0.w, b1v.x, b1v.y, b1v.z, b1v.w};
#pragma unroll
            for (int i = 0; i < 2; ++i)
#pragma unroll
                for (int j = 0; j < 8; ++j)
                    acc[i][j] = fmaf(av[i], bv[j], acc[i][j]);
        }
        __syncthreads();
    }

    // bias + ELU -> sH[c][m]
#pragma unroll
    for (int j = 0; j < 8; ++j) {
        int c = (j < 4) ? tx * 4 + j : 64 + tx * 4 + (j - 4);
        float bb = b1[c];
#pragma unroll
        for (int i = 0; i < 2; ++i) {
            float v = acc[i][j] + bb;
            v = (v > 0.f) ? v : (__expf(v) - 1.f);
            sH[c * 33 + ty * 2 + i] = v;
        }
    }

    // GEMM2: O = H @ W2 + b2
    float acc2[2][8];
#pragma unroll
    for (int i = 0; i < 2; ++i)
#pragma unroll
        for (int j = 0; j < 8; ++j) acc2[i][j] = 0.f;

    for (int ch2 = 0; ch2 < 4; ++ch2) {
#pragma unroll
        for (int it = 0; it < 4; ++it) {
            int idx = it * 256 + t;
            int kk = idx >> 5;
            int c4 = idx & 31;
            *(float4*)(sW2 + kk * 128 + c4 * 4) =
                *(const float4*)(W2 + (size_t)(ch2 * 32 + kk) * HID + c4 * 4);
        }
        __syncthreads();
#pragma unroll 4
        for (int k2 = 0; k2 < 32; ++k2) {
            float a0 = sH[(ch2 * 32 + k2) * 33 + ty * 2];
            float a1 = sH[(ch2 * 32 + k2) * 33 + ty * 2 + 1];
            float4 b0 = *(float4*)(sW2 + k2 * 128 + tx * 4);
            float4 b1v = *(float4*)(sW2 + k2 * 128 + 64 + tx * 4);
            float av[2] = {a0, a1};
            float bv[8] = {b0.x, b0.y, b0.z, b0.w, b1v.x, b1v.y, b1v.z, b1v.w};
#pragma unroll
            for (int i = 0; i < 2; ++i)
#pragma unroll
                for (int j = 0; j < 8; ++j)
                    acc2[i][j] = fmaf(av[i], bv[j], acc2[i][j]);
        }
        __syncthreads();
    }

#pragma unroll
    for (int j = 0; j < 8; ++j) {
        int c = (j < 4) ? tx * 4 + j : 64 + tx * 4 + (j - 4);
        float bb = b2[c];
#pragma unroll
        for (int i = 0; i < 2; ++i) acc2[i][j] += bb;
    }
#pragma unroll
    for (int i = 0; i < 2; ++i) {
        float p = 0.f;
#pragma unroll
        for (int j = 0; j < 8; ++j) p = fmaf(acc2[i][j], acc2[i][j], p);
        atomicAdd(&snorm[ty * 2 + i], p);
    }
    __syncthreads();
#pragma unroll
    for (int i = 0; i < 2; ++i) {
        int r = ty * 2 + i;
        float scale = 1.f / fmaxf(sqrtf(snorm[r]), 1e-12f);
#pragma unroll
        for (int half = 0; half < 2; ++half) {
            ushort4 h4;
            h4.x = f2h(acc2[i][half * 4 + 0] * scale);
            h4.y = f2h(acc2[i][half * 4 + 1] * scale);
            h4.z = f2h(acc2[i][half * 4 + 2] * scale);
            h4.w = f2h(acc2[i][half * 4 + 3] * scale);
            size_t off = (size_t)(R0 + r) * HID + half * 64 + tx * 4;
            *(ushort4*)(outH + off) = h4;
        }
    }

    // ---------------- phase B: pos bit-pack (grid-stride) ----------------
    const size_t nthreads = (size_t)gridDim.x * gridDim.y * 256;
    const size_t total_groups = (size_t)N_ROWS * N_ROWS / 4;  // int4 groups
#pragma unroll 8
    for (size_t g = (size_t)linb * 256 + t; g < total_groups; g += nthreads) {
        int4 v = *(const int4*)(pos + g * 4);
        unsigned nib = (v.x != 0 ? 1u : 0u) | (v.y != 0 ? 2u : 0u)
                     | (v.z != 0 ? 4u : 0u) | (v.w != 0 ? 8u : 0u);
        unsigned u = nib << ((t & 7) * 4);
        u |= (unsigned)__shfl_xor((int)u, 1);
        u |= (unsigned)__shfl_xor((int)u, 2);
        u |= (unsigned)__shfl_xor((int)u, 4);
        if ((t & 7) == 0) posbits[g >> 3] = u;
    }
}

// ---------------------------------------------------------------------------
// Kernel 2: MFMA sim, 128x128 tile/block, single-pass fp16. m97-style
// global_load_lds staging (32 KB, 2 ksteps of K=64) -> swizzled ds_read_b128.
// LDS total 38.9 KB -> 4 blocks/CU; __launch_bounds__(256,4) caps 128 VGPR.
// ---------------------------------------------------------------------------
__global__ __launch_bounds__(256, 4) void sim_mfma_kernel(
    const ushort* __restrict__ mh_, const ushort* __restrict__ sh_,
    const unsigned* __restrict__ posbits, float* __restrict__ sums)
{
    __shared__ float redR[128], redRP[128], redC[128], redCP[128];
    __shared__ unsigned sBR[128][4];  // rows I+m, bit b = pos[I+m][J+b]
    __shared__ unsigned sBC[128][4];  // rows J+n, bit b = pos[J+n][I+b]
    __shared__ __align__(16) char stage[32768];  // sA 16KB | sB 16KB

    const int t = threadIdx.x;
    const int lane = t & 63;
    const int wave = t >> 6;
    const int wr = wave >> 1, wc = wave & 1;
    const int I = blockIdx.y * 128;
    const int J = blockIdx.x * 128;
    const int r0 = wr * 64, c0 = wc * 64;
    const int lrow = lane & 15;
    const int quad = lane >> 4;

    // pos-bits: issue early, commit to LDS after the K-loop
    uint4 pb;
    if (t < 128) pb = *(const uint4*)(posbits + (size_t)(I + t) * (N_ROWS / 32) + J / 32);
    else         pb = *(const uint4*)(posbits + (size_t)(J + t - 128) * (N_ROWS / 32) + I / 32);

    const char* mhB = (const char*)mh_;
    const char* shB = (const char*)sh_;

    // staging: wave w covers rows [w*32, w*32+32) of A and B, 4 insts of
    // 8 rows each per matrix. lane l -> row l>>3, LDS chunk l&7 holds
    // global 16B chunk (l&7)^(l>>3 & 7)  [XOR row swizzle]
    const int rsub = lane >> 3;                 // 0..7
    const int cfetch = (lane & 7) ^ rsub;       // global 16B chunk of kstep slab
    const size_t gaBase = (size_t)(I + wave * 32 + rsub) * 256 + cfetch * 16;
    const size_t gbBase = (size_t)(J + wave * 32 + rsub) * 256 + cfetch * 16;
    char* sA = stage;
    char* sB = stage + 16384;
    const unsigned lsw = wave * 4096;           // wave's 4 KB staging region

    // fragment reads: row stride 128 B; slot = (quad + h*4) ^ (lrow&7)
    unsigned ra[4], rb[4];
#pragma unroll
    for (int s = 0; s < 4; ++s) {
        ra[s] = (unsigned)(r0 + s * 16 + lrow) * 128;
        rb[s] = (unsigned)(c0 + s * 16 + lrow) * 128;
    }
    const unsigned sl7 = (unsigned)(lrow & 7);

    f32x4 acc[4][4];
#pragma unroll
    for (int si = 0; si < 4; ++si)
#pragma unroll
        for (int sj = 0; sj < 4; ++sj) acc[si][sj] = (f32x4)0.f;

#pragma unroll
    for (int ks = 0; ks < 2; ++ks) {
        if (ks) __syncthreads();               // readers of previous kstep done
#pragma unroll
        for (int i = 0; i < 4; ++i) {
            gl2lds16(mhB + gaBase + i * 2048 + ks * 128, sA + lsw + i * 1024);
            gl2lds16(shB + gbBase + i * 2048 + ks * 128, sB + lsw + i * 1024);
        }
        __syncthreads();                       // vmcnt(0) drain + barrier

#pragma unroll
        for (int h = 0; h < 2; ++h) {
            const unsigned slot = ((unsigned)(quad + h * 4) ^ sl7) * 16;
            half8 a[4], b[4];
#pragma unroll
            for (int s = 0; s < 4; ++s) a[s] = *(const half8*)(sA + ra[s] + slot);
#pragma unroll
            for (int s = 0; s < 4; ++s) b[s] = *(const half8*)(sB + rb[s] + slot);
#pragma unroll
            for (int si = 0; si < 4; ++si)
#pragma unroll
                for (int sj = 0; sj < 4; ++sj)
                    acc[si][sj] = __builtin_amdgcn_mfma_f32_16x16x32_f16(
                        a[si], b[sj], acc[si][sj], 0, 0, 0);
        }
    }

    // sim = exp(dot / T)
#pragma unroll
    for (int si = 0; si < 4; ++si)
#pragma unroll
        for (int sj = 0; sj < 4; ++sj)
#pragma unroll
            for (int r = 0; r < 4; ++r)
                acc[si][sj][r] = __expf(acc[si][sj][r] * INV_TEMP);

    // commit pos bits + zero reductions; barrier also fences stage[] reuse
    if (t < 128) {
        redR[t] = 0.f; redRP[t] = 0.f;
        *(uint4*)sBR[t] = pb;
    } else {
        int u = t - 128;
        redC[u] = 0.f; redCP[u] = 0.f;
        *(uint4*)sBC[u] = pb;
    }
    __syncthreads();

    // ---- column sums (C-layout: col = lane&15, row = quad*4+reg) ----
#pragma unroll
    for (int sj = 0; sj < 4; ++sj) {
        int n = c0 + sj * 16 + lrow;
        float cs = 0.f, cp = 0.f;
#pragma unroll
        for (int si = 0; si < 4; ++si) {
            f32x4 v = acc[si][sj];
            cs += v[0] + v[1] + v[2] + v[3];
            int bb = r0 + si * 16 + quad * 4;
            unsigned bits = (sBC[n][bb >> 5] >> (bb & 31)) & 0xF;
            cp += (bits & 1u ? v[0] : 0.f) + (bits & 2u ? v[1] : 0.f)
                + (bits & 4u ? v[2] : 0.f) + (bits & 8u ? v[3] : 0.f);
        }
        cs += __shfl_xor(cs, 16); cs += __shfl_xor(cs, 32);
        cp += __shfl_xor(cp, 16); cp += __shfl_xor(cp, 32);
        if (lane < 16) {
            atomicAdd(&redC[c0 + sj * 16 + lane], cs);
            atomicAdd(&redCP[c0 + sj * 16 + lane], cp);
        }
    }

    // ---- row sums via per-wave LDS transpose (aliases stage[]) ----
    float* tw = (float*)(stage + wave * 4352);   // 16 x 68 floats
#pragma unroll
    for (int si = 0; si < 4; ++si) {
#pragma unroll
        for (int sj = 0; sj < 4; ++sj)
#pragma unroll
            for (int r = 0; r < 4; ++r)
                tw[(quad * 4 + r) * 68 + sj * 16 + lrow] = acc[si][sj][r];
        int row = lane & 15;
        int chunk = lane >> 4;
        const unsigned prw = sBR[r0 + si * 16 + row][(c0 >> 5) + (chunk >> 1)];
        float rs = 0.f, rp = 0.f;
#pragma unroll
        for (int c4 = 0; c4 < 4; ++c4) {
            f32x4 v = *(const f32x4*)(tw + row * 68 + chunk * 16 + c4 * 4);
            unsigned bits = (prw >> ((chunk & 1) * 16 + c4 * 4)) & 0xF;
            rs += v[0] + v[1] + v[2] + v[3];
            rp += (bits & 1u ? v[0] : 0.f) + (bits & 2u ? v[1] : 0.f)
                + (bits & 4u ? v[2] : 0.f) + (bits & 8u ? v[3] : 0.f);
        }
        rs += __shfl_xor(rs, 16); rs += __shfl_xor(rs, 32);
        rp += __shfl_xor(rp, 16); rp += __shfl_xor(rp, 32);
        if (lane < 16) {
            atomicAdd(&redR[r0 + si * 16 + lane], rs);
            atomicAdd(&redRP[r0 + si * 16 + lane], rp);
        }
    }
    __syncthreads();

    if (t < 128) {
        atomicAdd(&sums[I + t],              redR[t]);
        atomicAdd(&sums[N_ROWS + I + t],     redRP[t]);
        atomicAdd(&sums[2 * N_ROWS + J + t], redC[t]);
        atomicAdd(&sums[3 * N_ROWS + J + t], redCP[t]);
    }
}

// ---------------------------------------------------------------------------
// Kernel 3: final loss per element
// ---------------------------------------------------------------------------
__global__ __launch_bounds__(256) void finish_kernel(
    const float* __restrict__ sums, float* __restrict__ out)
{
    int i = blockIdx.x * 256 + threadIdx.x;
    if (i >= N_ROWS) return;
    float rsv = sums[i];
    float rpv = sums[N_ROWS + i];
    float csv = sums[2 * N_ROWS + i];
    float cpv = sums[3 * N_ROWS + i];
    float lmp = -logf(rpv / (rsv + EPSV) + EPSV);
    float lsc = -logf(cpv / (csv + EPSV) + EPSV);
    float a = 0.5f * lmp + 0.5f * lsc;
    if (!isfinite(a)) a = 0.f;
    out[i] = a;
}

extern "C" void kernel_launch(void* const* d_in, const int* in_sizes, int n_in,
                              void* d_out, int out_size, void* d_ws, size_t ws_size,
                              hipStream_t stream) {
    const float* z_mp = (const float*)d_in[0];
    const float* z_sc = (const float*)d_in[1];
    const float* W1   = (const float*)d_in[2];
    const float* b1   = (const float*)d_in[3];
    const float* W2   = (const float*)d_in[4];
    const float* b2   = (const float*)d_in[5];
    const int*   pos  = (const int*)d_in[6];
    float* out = (float*)d_out;

    ushort* wsu = (ushort*)d_ws;
    const size_t NV = (size_t)N_ROWS * HID;          // 1,048,576 elements
    ushort* mh = wsu;                                // fp16 mp_norm
    ushort* sh = wsu + NV;                           // fp16 sc_norm
    float* sums = (float*)(wsu + 2 * NV);            // 4*8192 floats = 128 KB
    unsigned* posbits = (unsigned*)(sums + 4 * N_ROWS);  // 8192*256 u32 = 8 MB

    prep_kernel<<<dim3(256, 2), 256, 0, stream>>>(
        z_mp, z_sc, W1, b1, W2, b2, mh, sh, pos, posbits, sums);
    sim_mfma_kernel<<<dim3(64, 64), 256, 0, stream>>>(mh, sh, posbits, sums);
    finish_kernel<<<N_ROWS / 256, 256, 0, stream>>>(sums, out);
}

// Round 10
// 437.762 us; speedup vs baseline: 1.0867x; 1.0867x over previous
//
#include <hip/hip_runtime.h>
#include <math.h>

#define N_ROWS 8192
#define IN_SZ 256
#define HID 128
#define INV_TEMP 5.0f
#define EPSV 1e-8f

typedef _Float16 half8 __attribute__((ext_vector_type(8)));
typedef float f32x4 __attribute__((ext_vector_type(4)));
typedef int i32x4 __attribute__((ext_vector_type(4)));

__device__ __forceinline__ ushort f2h(float v) {
    union { _Float16 h; ushort u; } c;
    c.h = (_Float16)v;
    return c.u;
}

// async global->LDS, 16 B per lane; LDS dest = uniform base + lane*16
__device__ __forceinline__ void gl2lds16(const void* g, void* l) {
    __builtin_amdgcn_global_load_lds(
        (const __attribute__((address_space(1))) unsigned*)g,
        (__attribute__((address_space(3))) unsigned*)l, 16, 0, 0);
}

// ---------------------------------------------------------------------------
// Kernel 1: lean bit-pack of pos (256 MB -> 8 MB). No LDS, 2048 blocks,
// unroll 8 for MLP, nontemporal loads (pure stream, never re-read).
// Blocks 0-3 zero the sums accumulators.
// ---------------------------------------------------------------------------
__global__ __launch_bounds__(256) void pack_kernel(
    const int* __restrict__ pos, unsigned* __restrict__ posbits,
    float* __restrict__ sums)
{
    const int t = threadIdx.x;
    if (blockIdx.x < 4) {
        float4 z4 = make_float4(0.f, 0.f, 0.f, 0.f);
        float* base = sums + (size_t)blockIdx.x * 8192 + t * 32;
#pragma unroll
        for (int i = 0; i < 8; ++i) *(float4*)(base + i * 4) = z4;
    }
    const size_t nthreads = (size_t)gridDim.x * 256;
    const size_t total_groups = (size_t)N_ROWS * N_ROWS / 4;  // int4 groups
#pragma unroll 8
    for (size_t g = (size_t)blockIdx.x * 256 + t; g < total_groups; g += nthreads) {
        i32x4 v = __builtin_nontemporal_load((const i32x4*)(pos + g * 4));
        unsigned nib = (v.x != 0 ? 1u : 0u) | (v.y != 0 ? 2u : 0u)
                     | (v.z != 0 ? 4u : 0u) | (v.w != 0 ? 8u : 0u);
        unsigned u = nib << ((t & 7) * 4);
        u |= (unsigned)__shfl_xor((int)u, 1);
        u |= (unsigned)__shfl_xor((int)u, 2);
        u |= (unsigned)__shfl_xor((int)u, 4);
        if ((t & 7) == 0) posbits[g >> 3] = u;
    }
}

// ---------------------------------------------------------------------------
// Kernel 2: zp = ELU(z@W1 + b1)@W2 + b2, L2-normalize rows, emit fp16.
// ---------------------------------------------------------------------------
__global__ __launch_bounds__(256) void proj_kernel(
    const float* __restrict__ z_mp, const float* __restrict__ z_sc,
    const float* __restrict__ W1, const float* __restrict__ b1,
    const float* __restrict__ W2, const float* __restrict__ b2,
    ushort* __restrict__ h_mp, ushort* __restrict__ h_sc)
{
    __shared__ float smem[10368];
    float* sZ  = smem;           // phase1: [k][m] 64 x 34 (pad)
    float* sW  = smem + 2176;    // phase1: [k][c] 64 x 128
    float* sH  = smem;           // phase2: [c][m] 128 x 33 (pad)
    float* sW2 = smem + 4224;    // phase2: [k2][c] 32 x 128
    float* snorm = smem + 8320;  // [32]

    const int t = threadIdx.x;
    const int sel = blockIdx.y;
    const int R0 = blockIdx.x * 32;
    const int tx = t & 15, ty = t >> 4;
    const float* z = (sel == 0) ? z_mp : z_sc;
    ushort* outH   = (sel == 0) ? h_mp : h_sc;

    if (t < 32) snorm[t] = 0.f;

    float acc[2][8];
#pragma unroll
    for (int i = 0; i < 2; ++i)
#pragma unroll
        for (int j = 0; j < 8; ++j) acc[i][j] = 0.f;

    // GEMM1: H = ELU(Z @ W1 + b1)
    for (int ch = 0; ch < 4; ++ch) {
#pragma unroll
        for (int it = 0; it < 2; ++it) {
            int idx = it * 256 + t;
            int k4 = idx >> 5;
            int m  = idx & 31;
            float4 v = *(const float4*)(z + (size_t)(R0 + m) * IN_SZ + ch * 64 + k4 * 4);
            sZ[(k4 * 4 + 0) * 34 + m] = v.x;
            sZ[(k4 * 4 + 1) * 34 + m] = v.y;
            sZ[(k4 * 4 + 2) * 34 + m] = v.z;
            sZ[(k4 * 4 + 3) * 34 + m] = v.w;
        }
#pragma unroll
        for (int it = 0; it < 8; ++it) {
            int idx = it * 256 + t;
            int kk = idx >> 5;
            int c4 = idx & 31;
            *(float4*)(sW + kk * 128 + c4 * 4) =
                *(const float4*)(W1 + (size_t)(ch * 64 + kk) * HID + c4 * 4);
        }
        __syncthreads();
#pragma unroll 4
        for (int k = 0; k < 64; ++k) {
            float2 a = *(const float2*)(sZ + k * 34 + ty * 2);
            float4 b0 = *(float4*)(sW + k * 128 + tx * 4);
            float4 b1v = *(float4*)(sW + k * 128 + 64 + tx * 4);
            float av[2] = {a.x, a.y};
            float bv[8] = {b0.x, b0.y, b0.z, b0.w, b1v.x, b1v.y, b1v.z, b1v.w};
#pragma unroll
            for (int i = 0; i < 2; ++i)
#pragma unroll
                for (int j = 0; j < 8; ++j)
                    acc[i][j] = fmaf(av[i], bv[j], acc[i][j]);
        }
        __syncthreads();
    }

    // bias + ELU -> sH[c][m]
#pragma unroll
    for (int j = 0; j < 8; ++j) {
        int c = (j < 4) ? tx * 4 + j : 64 + tx * 4 + (j - 4);
        float bb = b1[c];
#pragma unroll
        for (int i = 0; i < 2; ++i) {
            float v = acc[i][j] + bb;
            v = (v > 0.f) ? v : (__expf(v) - 1.f);
            sH[c * 33 + ty * 2 + i] = v;
        }
    }

    // GEMM2: O = H @ W2 + b2
    float acc2[2][8];
#pragma unroll
    for (int i = 0; i < 2; ++i)
#pragma unroll
        for (int j = 0; j < 8; ++j) acc2[i][j] = 0.f;

    for (int ch2 = 0; ch2 < 4; ++ch2) {
#pragma unroll
        for (int it = 0; it < 4; ++it) {
            int idx = it * 256 + t;
            int kk = idx >> 5;
            int c4 = idx & 31;
            *(float4*)(sW2 + kk * 128 + c4 * 4) =
                *(const float4*)(W2 + (size_t)(ch2 * 32 + kk) * HID + c4 * 4);
        }
        __syncthreads();
#pragma unroll 4
        for (int k2 = 0; k2 < 32; ++k2) {
            float a0 = sH[(ch2 * 32 + k2) * 33 + ty * 2];
            float a1 = sH[(ch2 * 32 + k2) * 33 + ty * 2 + 1];
            float4 b0 = *(float4*)(sW2 + k2 * 128 + tx * 4);
            float4 b1v = *(float4*)(sW2 + k2 * 128 + 64 + tx * 4);
            float av[2] = {a0, a1};
            float bv[8] = {b0.x, b0.y, b0.z, b0.w, b1v.x, b1v.y, b1v.z, b1v.w};
#pragma unroll
            for (int i = 0; i < 2; ++i)
#pragma unroll
                for (int j = 0; j < 8; ++j)
                    acc2[i][j] = fmaf(av[i], bv[j], acc2[i][j]);
        }
        __syncthreads();
    }

#pragma unroll
    for (int j = 0; j < 8; ++j) {
        int c = (j < 4) ? tx * 4 + j : 64 + tx * 4 + (j - 4);
        float bb = b2[c];
#pragma unroll
        for (int i = 0; i < 2; ++i) acc2[i][j] += bb;
    }
#pragma unroll
    for (int i = 0; i < 2; ++i) {
        float p = 0.f;
#pragma unroll
        for (int j = 0; j < 8; ++j) p = fmaf(acc2[i][j], acc2[i][j], p);
        atomicAdd(&snorm[ty * 2 + i], p);
    }
    __syncthreads();
#pragma unroll
    for (int i = 0; i < 2; ++i) {
        int r = ty * 2 + i;
        float scale = 1.f / fmaxf(sqrtf(snorm[r]), 1e-12f);
#pragma unroll
        for (int half = 0; half < 2; ++half) {
            ushort4 h4;
            h4.x = f2h(acc2[i][half * 4 + 0] * scale);
            h4.y = f2h(acc2[i][half * 4 + 1] * scale);
            h4.z = f2h(acc2[i][half * 4 + 2] * scale);
            h4.w = f2h(acc2[i][half * 4 + 3] * scale);
            size_t off = (size_t)(R0 + r) * HID + half * 64 + tx * 4;
            *(ushort4*)(outH + off) = h4;
        }
    }
}

// ---------------------------------------------------------------------------
// Kernel 3: MFMA sim, 128x128 tile/block, single-pass fp16. m97-style
// global_load_lds staging (32 KB, 2 ksteps of K=64) -> swizzled ds_read_b128.
// LDS total 38.9 KB -> 4 blocks/CU; __launch_bounds__(256,4) caps 128 VGPR.
// ---------------------------------------------------------------------------
__global__ __launch_bounds__(256, 4) void sim_mfma_kernel(
    const ushort* __restrict__ mh_, const ushort* __restrict__ sh_,
    const unsigned* __restrict__ posbits, float* __restrict__ sums)
{
    __shared__ float redR[128], redRP[128], redC[128], redCP[128];
    __shared__ unsigned sBR[128][4];  // rows I+m, bit b = pos[I+m][J+b]
    __shared__ unsigned sBC[128][4];  // rows J+n, bit b = pos[J+n][I+b]
    __shared__ __align__(16) char stage[32768];  // sA 16KB | sB 16KB

    const int t = threadIdx.x;
    const int lane = t & 63;
    const int wave = t >> 6;
    const int wr = wave >> 1, wc = wave & 1;
    const int I = blockIdx.y * 128;
    const int J = blockIdx.x * 128;
    const int r0 = wr * 64, c0 = wc * 64;
    const int lrow = lane & 15;
    const int quad = lane >> 4;

    // pos-bits: issue early, commit to LDS after the K-loop
    uint4 pb;
    if (t < 128) pb = *(const uint4*)(posbits + (size_t)(I + t) * (N_ROWS / 32) + J / 32);
    else         pb = *(const uint4*)(posbits + (size_t)(J + t - 128) * (N_ROWS / 32) + I / 32);

    const char* mhB = (const char*)mh_;
    const char* shB = (const char*)sh_;

    // staging: wave w covers rows [w*32, w*32+32) of A and B, 4 insts of
    // 8 rows each per matrix. lane l -> row l>>3, LDS chunk l&7 holds
    // global 16B chunk (l&7)^(l>>3 & 7)  [XOR row swizzle]
    const int rsub = lane >> 3;                 // 0..7
    const int cfetch = (lane & 7) ^ rsub;       // global 16B chunk of kstep slab
    const size_t gaBase = (size_t)(I + wave * 32 + rsub) * 256 + cfetch * 16;
    const size_t gbBase = (size_t)(J + wave * 32 + rsub) * 256 + cfetch * 16;
    char* sA = stage;
    char* sB = stage + 16384;
    const unsigned lsw = wave * 4096;           // wave's 4 KB staging region

    // fragment reads: row stride 128 B; slot = (quad + h*4) ^ (lrow&7)
    unsigned ra[4], rb[4];
#pragma unroll
    for (int s = 0; s < 4; ++s) {
        ra[s] = (unsigned)(r0 + s * 16 + lrow) * 128;
        rb[s] = (unsigned)(c0 + s * 16 + lrow) * 128;
    }
    const unsigned sl7 = (unsigned)(lrow & 7);

    f32x4 acc[4][4];
#pragma unroll
    for (int si = 0; si < 4; ++si)
#pragma unroll
        for (int sj = 0; sj < 4; ++sj) acc[si][sj] = (f32x4)0.f;

#pragma unroll
    for (int ks = 0; ks < 2; ++ks) {
        if (ks) __syncthreads();               // readers of previous kstep done
#pragma unroll
        for (int i = 0; i < 4; ++i) {
            gl2lds16(mhB + gaBase + i * 2048 + ks * 128, sA + lsw + i * 1024);
            gl2lds16(shB + gbBase + i * 2048 + ks * 128, sB + lsw + i * 1024);
        }
        __syncthreads();                       // vmcnt(0) drain + barrier

#pragma unroll
        for (int h = 0; h < 2; ++h) {
            const unsigned slot = ((unsigned)(quad + h * 4) ^ sl7) * 16;
            half8 a[4], b[4];
#pragma unroll
            for (int s = 0; s < 4; ++s) a[s] = *(const half8*)(sA + ra[s] + slot);
#pragma unroll
            for (int s = 0; s < 4; ++s) b[s] = *(const half8*)(sB + rb[s] + slot);
#pragma unroll
            for (int si = 0; si < 4; ++si)
#pragma unroll
                for (int sj = 0; sj < 4; ++sj)
                    acc[si][sj] = __builtin_amdgcn_mfma_f32_16x16x32_f16(
                        a[si], b[sj], acc[si][sj], 0, 0, 0);
        }
    }

    // sim = exp(dot / T)
#pragma unroll
    for (int si = 0; si < 4; ++si)
#pragma unroll
        for (int sj = 0; sj < 4; ++sj)
#pragma unroll
            for (int r = 0; r < 4; ++r)
                acc[si][sj][r] = __expf(acc[si][sj][r] * INV_TEMP);

    // commit pos bits + zero reductions; barrier also fences stage[] reuse
    if (t < 128) {
        redR[t] = 0.f; redRP[t] = 0.f;
        *(uint4*)sBR[t] = pb;
    } else {
        int u = t - 128;
        redC[u] = 0.f; redCP[u] = 0.f;
        *(uint4*)sBC[u] = pb;
    }
    __syncthreads();

    // ---- column sums (C-layout: col = lane&15, row = quad*4+reg) ----
#pragma unroll
    for (int sj = 0; sj < 4; ++sj) {
        int n = c0 + sj * 16 + lrow;
        float cs = 0.f, cp = 0.f;
#pragma unroll
        for (int si = 0; si < 4; ++si) {
            f32x4 v = acc[si][sj];
            cs += v[0] + v[1] + v[2] + v[3];
            int bb = r0 + si * 16 + quad * 4;
            unsigned bits = (sBC[n][bb >> 5] >> (bb & 31)) & 0xF;
            cp += (bits & 1u ? v[0] : 0.f) + (bits & 2u ? v[1] : 0.f)
                + (bits & 4u ? v[2] : 0.f) + (bits & 8u ? v[3] : 0.f);
        }
        cs += __shfl_xor(cs, 16); cs += __shfl_xor(cs, 32);
        cp += __shfl_xor(cp, 16); cp += __shfl_xor(cp, 32);
        if (lane < 16) {
            atomicAdd(&redC[c0 + sj * 16 + lane], cs);
            atomicAdd(&redCP[c0 + sj * 16 + lane], cp);
        }
    }

    // ---- row sums via per-wave LDS transpose (aliases stage[]) ----
    float* tw = (float*)(stage + wave * 4352);   // 16 x 68 floats
#pragma unroll
    for (int si = 0; si < 4; ++si) {
#pragma unroll
        for (int sj = 0; sj < 4; ++sj)
#pragma unroll
            for (int r = 0; r < 4; ++r)
                tw[(quad * 4 + r) * 68 + sj * 16 + lrow] = acc[si][sj][r];
        int row = lane & 15;
        int chunk = lane >> 4;
        const unsigned prw = sBR[r0 + si * 16 + row][(c0 >> 5) + (chunk >> 1)];
        float rs = 0.f, rp = 0.f;
#pragma unroll
        for (int c4 = 0; c4 < 4; ++c4) {
            f32x4 v = *(const f32x4*)(tw + row * 68 + chunk * 16 + c4 * 4);
            unsigned bits = (prw >> ((chunk & 1) * 16 + c4 * 4)) & 0xF;
            rs += v[0] + v[1] + v[2] + v[3];
            rp += (bits & 1u ? v[0] : 0.f) + (bits & 2u ? v[1] : 0.f)
                + (bits & 4u ? v[2] : 0.f) + (bits & 8u ? v[3] : 0.f);
        }
        rs += __shfl_xor(rs, 16); rs += __shfl_xor(rs, 32);
        rp += __shfl_xor(rp, 16); rp += __shfl_xor(rp, 32);
        if (lane < 16) {
            atomicAdd(&redR[r0 + si * 16 + lane], rs);
            atomicAdd(&redRP[r0 + si * 16 + lane], rp);
        }
    }
    __syncthreads();

    if (t < 128) {
        atomicAdd(&sums[I + t],              redR[t]);
        atomicAdd(&sums[N_ROWS + I + t],     redRP[t]);
        atomicAdd(&sums[2 * N_ROWS + J + t], redC[t]);
        atomicAdd(&sums[3 * N_ROWS + J + t], redCP[t]);
    }
}

// ---------------------------------------------------------------------------
// Kernel 4: final loss per element
// ---------------------------------------------------------------------------
__global__ __launch_bounds__(256) void finish_kernel(
    const float* __restrict__ sums, float* __restrict__ out)
{
    int i = blockIdx.x * 256 + threadIdx.x;
    if (i >= N_ROWS) return;
    float rsv = sums[i];
    float rpv = sums[N_ROWS + i];
    float csv = sums[2 * N_ROWS + i];
    float cpv = sums[3 * N_ROWS + i];
    float lmp = -logf(rpv / (rsv + EPSV) + EPSV);
    float lsc = -logf(cpv / (csv + EPSV) + EPSV);
    float a = 0.5f * lmp + 0.5f * lsc;
    if (!isfinite(a)) a = 0.f;
    out[i] = a;
}

extern "C" void kernel_launch(void* const* d_in, const int* in_sizes, int n_in,
                              void* d_out, int out_size, void* d_ws, size_t ws_size,
                              hipStream_t stream) {
    const float* z_mp = (const float*)d_in[0];
    const float* z_sc = (const float*)d_in[1];
    const float* W1   = (const float*)d_in[2];
    const float* b1   = (const float*)d_in[3];
    const float* W2   = (const float*)d_in[4];
    const float* b2   = (const float*)d_in[5];
    const int*   pos  = (const int*)d_in[6];
    float* out = (float*)d_out;

    ushort* wsu = (ushort*)d_ws;
    const size_t NV = (size_t)N_ROWS * HID;          // 1,048,576 elements
    ushort* mh = wsu;                                // fp16 mp_norm
    ushort* sh = wsu + NV;                           // fp16 sc_norm
    float* sums = (float*)(wsu + 2 * NV);            // 4*8192 floats = 128 KB
    unsigned* posbits = (unsigned*)(sums + 4 * N_ROWS);  // 8192*256 u32 = 8 MB

    pack_kernel<<<2048, 256, 0, stream>>>(pos, posbits, sums);
    proj_kernel<<<dim3(256, 2), 256, 0, stream>>>(
        z_mp, z_sc, W1, b1, W2, b2, mh, sh);
    sim_mfma_kernel<<<dim3(64, 64), 256, 0, stream>>>(mh, sh, posbits, sums);
    finish_kernel<<<N_ROWS / 256, 256, 0, stream>>>(sums, out);
}